// Round 1
// baseline (1522.626 us; speedup 1.0000x reference)
//
#include <hip/hip_runtime.h>

#define BATCH 16
#define NQ    16384      // N = 128*128
#define CH    64         // EMBED
#define NKV   256        // (128/8)*(128/8)
#define EPS_LN 1e-5f

// ---------------- Kernel A: conv8x8s8 + LayerNorm + KV projection ----------------
// grid: BATCH*256 blocks, 256 threads. One block per (b, patch).
__global__ __launch_bounds__(256) void kv_kernel(
    const float* __restrict__ inp,     // [B, 16384, 64]
    const float* __restrict__ conv_w,  // [8,8,64,64] HWIO
    const float* __restrict__ conv_b,  // [64]
    const float* __restrict__ gamma,   // [64]
    const float* __restrict__ beta,    // [64]
    const float* __restrict__ Wkv,     // [64,128]
    const float* __restrict__ bkv,     // [128]
    float* __restrict__ Kt,            // [B,64,256]  (d-major, j-minor)
    float* __restrict__ V)             // [B,256,64]
{
    __shared__ float xp[4096];     // patch: [row=i*8+j][cin]
    __shared__ float psum[4 * 64];
    __shared__ float yln[64];

    const int blk = blockIdx.x;
    const int b  = blk >> 8;
    const int p  = blk & 255;
    const int ph = p >> 4, pw = p & 15;
    const int t  = threadIdx.x;

    // stage the 8x8x64 input patch into LDS (coalesced 64-float rows)
    for (int k = 0; k < 16; ++k) {
        int idx = t + k * 256;           // 0..4095
        int row = idx >> 6;              // i*8 + j
        int cin = idx & 63;
        int i = row >> 3, j = row & 7;
        int n = (ph * 8 + i) * 128 + (pw * 8 + j);
        xp[idx] = inp[((size_t)b * NQ + n) * CH + cin];
    }
    __syncthreads();

    // conv as K=4096 dot: 4 partial threads per cout
    const int cout = t & 63;
    const int part = t >> 6;
    float sum = 0.f;
    for (int row = part * 16; row < part * 16 + 16; ++row) {
        const float* cw = conv_w + (size_t)row * 64 * 64 + cout;
        const float* xr = xp + row * 64;
        #pragma unroll
        for (int cin = 0; cin < 64; ++cin)
            sum += xr[cin] * cw[(size_t)cin * 64];
    }
    psum[part * 64 + cout] = sum;
    __syncthreads();

    // reduce partials + bias, then LayerNorm over 64 channels (wave 0 only)
    if (t < 64) {
        float x = psum[t] + psum[64 + t] + psum[128 + t] + psum[192 + t] + conv_b[t];
        float s = x;
        #pragma unroll
        for (int off = 32; off >= 1; off >>= 1) s += __shfl_xor(s, off, 64);
        float mean = s * (1.f / 64.f);
        float d = x - mean;
        float v2 = d * d;
        #pragma unroll
        for (int off = 32; off >= 1; off >>= 1) v2 += __shfl_xor(v2, off, 64);
        float var = v2 * (1.f / 64.f);
        yln[t] = d * rsqrtf(var + EPS_LN) * gamma[t] + beta[t];
    }
    __syncthreads();

    // KV projection: cols 0..63 -> K, 64..127 -> V
    if (t < 128) {
        float acc = bkv[t];
        #pragma unroll
        for (int c = 0; c < 64; ++c)
            acc += yln[c] * Wkv[c * 128 + t];
        if (t < 64)
            Kt[((size_t)b * 64 + t) * 256 + p] = acc;       // transposed store
        else
            V[((size_t)b * 256 + p) * 64 + (t - 64)] = acc;
    }
}

// ---------------- Kernel B: q-proj + attention + out-proj (one wave per query) ----------------
// grid: BATCH*NQ/4 blocks, 256 threads (4 waves/block)
__global__ __launch_bounds__(256) void attn_kernel(
    const float* __restrict__ inp,   // [B, 16384, 64]
    const float* __restrict__ Wq,    // [64,64]
    const float* __restrict__ bq,    // [64]
    const float* __restrict__ Kt,    // [B,64,256]
    const float* __restrict__ V,     // [B,256,64]
    const float* __restrict__ Wo,    // [64,64]
    const float* __restrict__ bo,    // [64]
    float* __restrict__ out)         // [B,16384,64]
{
    __shared__ float xs[4][64];
    __shared__ float qs[4][64];
    __shared__ float Ps[4][256];

    const int w    = threadIdx.x >> 6;
    const int lane = threadIdx.x & 63;
    const int qid  = blockIdx.x * 4 + w;
    const int b    = qid >> 14;          // / 16384
    const size_t rowoff = (size_t)qid * 64;

    // stage input row
    xs[w][lane] = inp[rowoff + lane];
    __syncthreads();

    // q projection (scale folded in)
    float q = bq[lane];
    #pragma unroll
    for (int c = 0; c < 64; ++c)
        q += xs[w][c] * Wq[c * 64 + lane];
    q *= 0.125f;                          // 1/sqrt(64)
    qs[w][lane] = q;
    __syncthreads();

    // scores: 4 kv per lane, coalesced reads of Kt columns
    const float* Ktb = Kt + (size_t)b * (64 * 256);
    float s0 = 0.f, s1 = 0.f, s2 = 0.f, s3 = 0.f;
    #pragma unroll 8
    for (int d = 0; d < 64; ++d) {
        float qd = qs[w][d];
        const float* kr = Ktb + d * 256 + lane;
        s0 += qd * kr[0];
        s1 += qd * kr[64];
        s2 += qd * kr[128];
        s3 += qd * kr[192];
    }

    // softmax over 256 (wave allreduce)
    float m = fmaxf(fmaxf(s0, s1), fmaxf(s2, s3));
    #pragma unroll
    for (int off = 32; off >= 1; off >>= 1) m = fmaxf(m, __shfl_xor(m, off, 64));
    float p0 = __expf(s0 - m), p1 = __expf(s1 - m), p2 = __expf(s2 - m), p3 = __expf(s3 - m);
    float lsum = p0 + p1 + p2 + p3;
    #pragma unroll
    for (int off = 32; off >= 1; off >>= 1) lsum += __shfl_xor(lsum, off, 64);
    const float inv = 1.f / lsum;
    Ps[w][lane] = p0; Ps[w][lane + 64] = p1; Ps[w][lane + 128] = p2; Ps[w][lane + 192] = p3;
    __syncthreads();

    // PV: lane = output channel, coalesced V reads
    const float* Vb = V + (size_t)b * (256 * 64);
    float acc = 0.f;
    #pragma unroll 8
    for (int j = 0; j < 256; ++j)
        acc += Ps[w][j] * Vb[j * 64 + lane];
    acc *= inv;

    // out projection (reuse xs)
    __syncthreads();
    xs[w][lane] = acc;
    __syncthreads();
    float o = bo[lane];
    #pragma unroll
    for (int c = 0; c < 64; ++c)
        o += xs[w][c] * Wo[c * 64 + lane];
    out[rowoff + lane] = o;
}

extern "C" void kernel_launch(void* const* d_in, const int* in_sizes, int n_in,
                              void* d_out, int out_size, void* d_ws, size_t ws_size,
                              hipStream_t stream) {
    const float* inp     = (const float*)d_in[0];
    const float* Wq      = (const float*)d_in[1];
    const float* bq      = (const float*)d_in[2];
    const float* Wkv     = (const float*)d_in[3];
    const float* bkv     = (const float*)d_in[4];
    const float* Wo      = (const float*)d_in[5];
    const float* bo      = (const float*)d_in[6];
    const float* conv_w  = (const float*)d_in[7];
    const float* conv_b  = (const float*)d_in[8];
    const float* gamma   = (const float*)d_in[9];
    const float* beta    = (const float*)d_in[10];

    float* Kt = (float*)d_ws;                    // 16*64*256 = 262144 floats (1 MiB)
    float* V  = Kt + (size_t)BATCH * 64 * 256;   // 1 MiB

    kv_kernel<<<BATCH * 256, 256, 0, stream>>>(inp, conv_w, conv_b, gamma, beta,
                                               Wkv, bkv, Kt, V);
    attn_kernel<<<(BATCH * NQ) / 4, 256, 0, stream>>>(inp, Wq, bq, Kt, V, Wo, bo,
                                                      (float*)d_out);
}

// Round 2
// 414.984 us; speedup vs baseline: 3.6691x; 3.6691x over previous
//
#include <hip/hip_runtime.h>

#define BATCH 16
#define NQ    16384      // N = 128*128
#define CH    64         // EMBED
#define NKV   256        // (128/8)*(128/8)
#define EPS_LN 1e-5f

typedef __attribute__((ext_vector_type(8))) short short8;
typedef __attribute__((ext_vector_type(4))) float f32x4;

#define MFMA16(a, b, c) __builtin_amdgcn_mfma_f32_16x16x32_bf16((a), (b), (c), 0, 0, 0)

__device__ __forceinline__ unsigned short f2bf(float f) {
    unsigned int u = __builtin_bit_cast(unsigned int, f);
    u += 0x7FFFu + ((u >> 16) & 1u);   // RNE
    return (unsigned short)(u >> 16);
}

// ---------------- Prep: transpose Wq / Wo to bf16 [n][k] (B-operand layout) ----------------
__global__ __launch_bounds__(256) void prep_kernel(
    const float* __restrict__ Wq, const float* __restrict__ Wo,
    unsigned short* __restrict__ Wq_t, unsigned short* __restrict__ Wo_t)
{
    for (int i = threadIdx.x; i < 4096; i += 256) {
        int d = i >> 6, c = i & 63;
        Wq_t[d * 64 + c] = f2bf(Wq[c * 64 + d]);
        Wo_t[d * 64 + c] = f2bf(Wo[c * 64 + d]);
    }
}

// ---------------- Kernel A: conv8x8s8 + LayerNorm + KV projection ----------------
// grid: BATCH*256 blocks, 256 threads. One block per (b, patch).
__global__ __launch_bounds__(256) void kv_kernel(
    const float* __restrict__ inp,     // [B, 16384, 64]
    const float* __restrict__ conv_w,  // [8,8,64,64] HWIO
    const float* __restrict__ conv_b,  // [64]
    const float* __restrict__ gamma,   // [64]
    const float* __restrict__ beta,    // [64]
    const float* __restrict__ Wkv,     // [64,128]
    const float* __restrict__ bkv,     // [128]
    unsigned short* __restrict__ Kb,   // [B,256,64] bf16  (j-major, d contig)
    unsigned short* __restrict__ Vt)   // [B,64,256]  bf16 (d-major, j contig)
{
    __shared__ float xp[4096];     // patch: [row=i*8+j][cin]
    __shared__ float psum[4 * 64];
    __shared__ float yln[64];

    const int blk = blockIdx.x;
    const int b  = blk >> 8;
    const int p  = blk & 255;
    const int ph = p >> 4, pw = p & 15;
    const int t  = threadIdx.x;

    for (int k = 0; k < 16; ++k) {
        int idx = t + k * 256;
        int row = idx >> 6;
        int cin = idx & 63;
        int i = row >> 3, j = row & 7;
        int n = (ph * 8 + i) * 128 + (pw * 8 + j);
        xp[idx] = inp[((size_t)b * NQ + n) * CH + cin];
    }
    __syncthreads();

    const int cout = t & 63;
    const int part = t >> 6;
    float sum = 0.f;
    for (int row = part * 16; row < part * 16 + 16; ++row) {
        const float* cw = conv_w + (size_t)row * 64 * 64 + cout;
        const float* xr = xp + row * 64;
        #pragma unroll
        for (int cin = 0; cin < 64; ++cin)
            sum += xr[cin] * cw[(size_t)cin * 64];
    }
    psum[part * 64 + cout] = sum;
    __syncthreads();

    if (t < 64) {
        float x = psum[t] + psum[64 + t] + psum[128 + t] + psum[192 + t] + conv_b[t];
        float s = x;
        #pragma unroll
        for (int off = 32; off >= 1; off >>= 1) s += __shfl_xor(s, off, 64);
        float mean = s * (1.f / 64.f);
        float d = x - mean;
        float v2 = d * d;
        #pragma unroll
        for (int off = 32; off >= 1; off >>= 1) v2 += __shfl_xor(v2, off, 64);
        float var = v2 * (1.f / 64.f);
        yln[t] = d * rsqrtf(var + EPS_LN) * gamma[t] + beta[t];
    }
    __syncthreads();

    if (t < 128) {
        float acc = bkv[t];
        #pragma unroll
        for (int c = 0; c < 64; ++c)
            acc += yln[c] * Wkv[c * 128 + t];
        if (t < 64)
            Kb[((size_t)b * 256 + p) * 64 + t] = f2bf(acc);
        else
            Vt[((size_t)b * 64 + (t - 64)) * 256 + p] = f2bf(acc);
    }
}

// ---------------- Kernel B: fused MFMA attention ----------------
// grid: BATCH*NQ/64 blocks, 256 threads (4 waves). Wave w: query rows [blk*64+16w, +16).
// No cross-wave LDS sharing -> no __syncthreads anywhere.
__global__ __launch_bounds__(256, 3) void attn_mfma(
    const float* __restrict__ inp,          // [B*NQ, 64]
    const unsigned short* __restrict__ Wq_t,// [64][64] bf16, [d][c]
    const float* __restrict__ bq,           // [64]
    const unsigned short* __restrict__ Kb,  // [B,256,64] bf16
    const unsigned short* __restrict__ Vt,  // [B,64,256] bf16
    const unsigned short* __restrict__ Wo_t,// [64][64] bf16, [e][c]
    const float* __restrict__ bo,           // [64]
    float* __restrict__ out)                // [B*NQ, 64]
{
    __shared__ unsigned short Xbuf[4][16][72];   // A-operand staging (row-major, k contig, +8 pad)
    __shared__ unsigned short Ps[4][16][264];    // P staging (+8 pad)

    const int w    = threadIdx.x >> 6;
    const int lane = threadIdx.x & 63;
    const int l15  = lane & 15;
    const int q4   = lane >> 4;
    const int b    = blockIdx.x >> 8;            // 256 blocks per batch
    const int m0   = blockIdx.x * 64 + w * 16;   // flat query row base for this wave

    // ---- stage X strip (16x64 fp32 -> bf16 LDS) ----
    const float* xrow = inp + (size_t)m0 * 64;
    #pragma unroll
    for (int r = 0; r < 16; ++r)
        Xbuf[w][r][lane] = f2bf(xrow[r * 64 + lane]);

    short8 a0 = *(const short8*)&Xbuf[w][l15][q4 * 8];
    short8 a1 = *(const short8*)&Xbuf[w][l15][32 + q4 * 8];

    // ---- q-projection: Q = X * Wq ----
    f32x4 zero = {0.f, 0.f, 0.f, 0.f};
    f32x4 qacc[4];
    #pragma unroll
    for (int t = 0; t < 4; ++t) {
        const short8 b0 = *(const short8*)(Wq_t + (t * 16 + l15) * 64 + q4 * 8);
        const short8 b1 = *(const short8*)(Wq_t + (t * 16 + l15) * 64 + 32 + q4 * 8);
        qacc[t] = MFMA16(a1, b1, MFMA16(a0, b0, zero));
    }
    // bias + scale, back through LDS (C-layout -> A-layout)
    #pragma unroll
    for (int t = 0; t < 4; ++t)
        #pragma unroll
        for (int r = 0; r < 4; ++r)
            Xbuf[w][q4 * 4 + r][t * 16 + l15] = f2bf((qacc[t][r] + bq[t * 16 + l15]) * 0.125f);

    short8 qa0 = *(const short8*)&Xbuf[w][l15][q4 * 8];
    short8 qa1 = *(const short8*)&Xbuf[w][l15][32 + q4 * 8];

    // ---- scores: S = Q * K^T  (Kb rows are B-operand [n][k] fragments) ----
    const unsigned short* Kbb = Kb + (size_t)b * 256 * 64;
    f32x4 sacc[16];
    #pragma unroll
    for (int t = 0; t < 16; ++t) {
        const short8 b0 = *(const short8*)(Kbb + (t * 16 + l15) * 64 + q4 * 8);
        const short8 b1 = *(const short8*)(Kbb + (t * 16 + l15) * 64 + 32 + q4 * 8);
        sacc[t] = MFMA16(qa1, b1, MFMA16(qa0, b0, zero));
    }

    // ---- softmax over 256 cols (cols live on the 16-lane group {same q4}) ----
    float mx[4] = {-1e30f, -1e30f, -1e30f, -1e30f};
    #pragma unroll
    for (int t = 0; t < 16; ++t)
        #pragma unroll
        for (int r = 0; r < 4; ++r)
            mx[r] = fmaxf(mx[r], sacc[t][r]);
    #pragma unroll
    for (int r = 0; r < 4; ++r) {
        mx[r] = fmaxf(mx[r], __shfl_xor(mx[r], 1));
        mx[r] = fmaxf(mx[r], __shfl_xor(mx[r], 2));
        mx[r] = fmaxf(mx[r], __shfl_xor(mx[r], 4));
        mx[r] = fmaxf(mx[r], __shfl_xor(mx[r], 8));
    }
    float sm[4] = {0.f, 0.f, 0.f, 0.f};
    #pragma unroll
    for (int t = 0; t < 16; ++t)
        #pragma unroll
        for (int r = 0; r < 4; ++r) {
            float p = __expf(sacc[t][r] - mx[r]);
            sacc[t][r] = p;
            sm[r] += p;
        }
    float inv[4];
    #pragma unroll
    for (int r = 0; r < 4; ++r) {
        sm[r] += __shfl_xor(sm[r], 1);
        sm[r] += __shfl_xor(sm[r], 2);
        sm[r] += __shfl_xor(sm[r], 4);
        sm[r] += __shfl_xor(sm[r], 8);
        inv[r] = 1.f / sm[r];
    }
    // P -> LDS (C-layout -> A-layout), bf16
    #pragma unroll
    for (int t = 0; t < 16; ++t)
        #pragma unroll
        for (int r = 0; r < 4; ++r)
            Ps[w][q4 * 4 + r][t * 16 + l15] = f2bf(sacc[t][r]);

    short8 pa[8];
    #pragma unroll
    for (int kc = 0; kc < 8; ++kc)
        pa[kc] = *(const short8*)&Ps[w][l15][kc * 32 + q4 * 8];

    // ---- PV: O = P * V  (Vt rows are B-operand [n][k] fragments) ----
    const unsigned short* Vtb = Vt + (size_t)b * 64 * 256;
    f32x4 oacc[4];
    #pragma unroll
    for (int t = 0; t < 4; ++t) {
        f32x4 acc = zero;
        #pragma unroll
        for (int kc = 0; kc < 8; ++kc) {
            const short8 bf = *(const short8*)(Vtb + (t * 16 + l15) * 256 + kc * 32 + q4 * 8);
            acc = MFMA16(pa[kc], bf, acc);
        }
        oacc[t] = acc;
    }
    // normalize rows (row = q4*4+r matches inv[r]) and stage for o-proj
    #pragma unroll
    for (int t = 0; t < 4; ++t)
        #pragma unroll
        for (int r = 0; r < 4; ++r)
            Xbuf[w][q4 * 4 + r][t * 16 + l15] = f2bf(oacc[t][r] * inv[r]);

    short8 oa0 = *(const short8*)&Xbuf[w][l15][q4 * 8];
    short8 oa1 = *(const short8*)&Xbuf[w][l15][32 + q4 * 8];

    // ---- o-projection + bias + store ----
    #pragma unroll
    for (int t = 0; t < 4; ++t) {
        const short8 b0 = *(const short8*)(Wo_t + (t * 16 + l15) * 64 + q4 * 8);
        const short8 b1 = *(const short8*)(Wo_t + (t * 16 + l15) * 64 + 32 + q4 * 8);
        f32x4 fin = MFMA16(oa1, b1, MFMA16(oa0, b0, zero));
        const float bias = bo[t * 16 + l15];
        #pragma unroll
        for (int r = 0; r < 4; ++r)
            out[(size_t)(m0 + q4 * 4 + r) * 64 + t * 16 + l15] = fin[r] + bias;
    }
}

extern "C" void kernel_launch(void* const* d_in, const int* in_sizes, int n_in,
                              void* d_out, int out_size, void* d_ws, size_t ws_size,
                              hipStream_t stream) {
    const float* inp     = (const float*)d_in[0];
    const float* Wq      = (const float*)d_in[1];
    const float* bq      = (const float*)d_in[2];
    const float* Wkv     = (const float*)d_in[3];
    const float* bkv     = (const float*)d_in[4];
    const float* Wo      = (const float*)d_in[5];
    const float* bo      = (const float*)d_in[6];
    const float* conv_w  = (const float*)d_in[7];
    const float* conv_b  = (const float*)d_in[8];
    const float* gamma   = (const float*)d_in[9];
    const float* beta    = (const float*)d_in[10];

    char* ws = (char*)d_ws;
    unsigned short* Kb   = (unsigned short*)(ws);                 // 16*256*64*2 = 512 KiB
    unsigned short* Vt   = (unsigned short*)(ws + 524288);        // 512 KiB
    unsigned short* Wq_t = (unsigned short*)(ws + 1048576);       // 8 KiB
    unsigned short* Wo_t = (unsigned short*)(ws + 1056768);       // 8 KiB

    prep_kernel<<<1, 256, 0, stream>>>(Wq, Wo, Wq_t, Wo_t);
    kv_kernel<<<BATCH * 256, 256, 0, stream>>>(inp, conv_w, conv_b, gamma, beta,
                                               Wkv, bkv, Kb, Vt);
    attn_mfma<<<(BATCH * NQ) / 64, 256, 0, stream>>>(inp, Wq_t, bq, Kb, Vt,
                                                     Wo_t, bo, (float*)d_out);
}

// Round 3
// 308.097 us; speedup vs baseline: 4.9420x; 1.3469x over previous
//
#include <hip/hip_runtime.h>

#define BATCH 16
#define NQ    16384      // N = 128*128
#define CH    64         // EMBED
#define NKV   256        // (128/8)*(128/8)
#define EPS_LN 1e-5f

typedef __attribute__((ext_vector_type(8))) short short8;
typedef __attribute__((ext_vector_type(4))) float f32x4;

#define MFMA16(a, b, c) __builtin_amdgcn_mfma_f32_16x16x32_bf16((a), (b), (c), 0, 0, 0)

__device__ __forceinline__ unsigned short f2bf(float f) {
    unsigned int u = __builtin_bit_cast(unsigned int, f);
    u += 0x7FFFu + ((u >> 16) & 1u);   // RNE
    return (unsigned short)(u >> 16);
}

// ---------------- Prep: bf16 B-operand layouts for Wq, Wo, conv_w ----------------
// grid: 64 blocks x 256. Block b builds Wc_t row cout=b; block 0 also does Wq/Wo.
__global__ __launch_bounds__(256) void prep_kernel(
    const float* __restrict__ Wq, const float* __restrict__ Wo,
    const float* __restrict__ conv_w,
    unsigned short* __restrict__ Wq_t, unsigned short* __restrict__ Wo_t,
    unsigned short* __restrict__ Wc_t)   // [64][4096] bf16
{
    const int cout = blockIdx.x;
    for (int k = threadIdx.x; k < 4096; k += 256)
        Wc_t[cout * 4096 + k] = f2bf(conv_w[(size_t)k * 64 + cout]);
    if (cout == 0) {
        for (int i = threadIdx.x; i < 4096; i += 256) {
            int d = i >> 6, c = i & 63;
            Wq_t[d * 64 + c] = f2bf(Wq[c * 64 + d]);
            Wo_t[d * 64 + c] = f2bf(Wo[c * 64 + d]);
        }
    }
}

// ---------------- Kernel A: conv8x8s8 (MFMA) + LayerNorm + KV projection ----------------
// grid: BATCH*16 = 256 blocks (one per (b, ph)), 256 threads = 4 waves.
// Wave w covers K-quarter (image rows 2w, 2w+1 of the patch row); all 64 couts.
__global__ __launch_bounds__(256) void kv_mfma(
    const float* __restrict__ inp,      // [B, 16384, 64]
    const unsigned short* __restrict__ Wc,  // [64][4096] bf16 (cout-major)
    const float* __restrict__ conv_b,   // [64]
    const float* __restrict__ gamma,    // [64]
    const float* __restrict__ beta,     // [64]
    const float* __restrict__ Wkv,      // [64,128]
    const float* __restrict__ bkv,      // [128]
    unsigned short* __restrict__ Kb,    // [B,256,64] bf16
    unsigned short* __restrict__ Vt)    // [B,64,256] bf16
{
    __shared__ unsigned short Xs[4][16][520];  // per-wave A staging: [patch m][k-chunk 512] (+8 pad)
    __shared__ float psum[4][16][68];          // per-wave C partials [m][cout]
    __shared__ float yln[16][68];

    const int t    = threadIdx.x;
    const int w    = t >> 6;
    const int lane = t & 63;
    const int l15  = lane & 15;
    const int q4   = lane >> 4;
    const int b    = blockIdx.x >> 4;
    const int ph   = blockIdx.x & 15;

    unsigned short* Xw = &Xs[w][0][0];

    f32x4 acc[4] = {{0,0,0,0},{0,0,0,0},{0,0,0,0},{0,0,0,0}};

    for (int ci = 0; ci < 2; ++ci) {
        const int i = 2 * w + ci;                       // pixel row within patch
        const float* src = inp + ((size_t)(b * 128 + ph * 8 + i) * 128) * 64;

        // stage one image row (8192 floats) into this wave's LDS region, bf16
        #pragma unroll 4
        for (int pass = 0; pass < 16; ++pass) {
            const int e = pass * 512 + lane * 8;        // 8 consecutive floats
            const float4 f0 = *(const float4*)(src + e);
            const float4 f1 = *(const float4*)(src + e + 4);
            const int col = e >> 6;                     // image col = pw*8 + j
            const int cin = e & 63;
            const int pw = col >> 3, j = col & 7;
            short8 v;
            v[0] = f2bf(f0.x); v[1] = f2bf(f0.y); v[2] = f2bf(f0.z); v[3] = f2bf(f0.w);
            v[4] = f2bf(f1.x); v[5] = f2bf(f1.y); v[6] = f2bf(f1.z); v[7] = f2bf(f1.w);
            *(short8*)(Xw + pw * 520 + j * 64 + cin) = v;
        }
        // per-wave region: no barrier needed (DS pipe is in-order per wave)

        #pragma unroll 4
        for (int s = 0; s < 16; ++s) {
            const short8 af = *(const short8*)(Xw + l15 * 520 + s * 32 + q4 * 8);
            const int kg = i * 512 + s * 32 + q4 * 8;
            #pragma unroll
            for (int nt = 0; nt < 4; ++nt) {
                const short8 bf = *(const short8*)(Wc + (size_t)(nt * 16 + l15) * 4096 + kg);
                acc[nt] = MFMA16(af, bf, acc[nt]);
            }
        }
    }

    // write K-partials (C-layout: col=l15, row=q4*4+r)
    #pragma unroll
    for (int nt = 0; nt < 4; ++nt)
        #pragma unroll
        for (int r = 0; r < 4; ++r)
            psum[w][q4 * 4 + r][nt * 16 + l15] = acc[nt][r];
    __syncthreads();

    // ---- LayerNorm: 16 threads per patch, 4 channels each ----
    {
        const int patch = t >> 4;
        const int g = t & 15;
        float x[4], s = 0.f;
        #pragma unroll
        for (int cc = 0; cc < 4; ++cc) {
            const int c = g + cc * 16;
            x[cc] = psum[0][patch][c] + psum[1][patch][c]
                  + psum[2][patch][c] + psum[3][patch][c] + conv_b[c];
            s += x[cc];
        }
        #pragma unroll
        for (int off = 8; off >= 1; off >>= 1) s += __shfl_xor(s, off, 16);
        const float mean = s * (1.f / 64.f);
        float v2 = 0.f;
        #pragma unroll
        for (int cc = 0; cc < 4; ++cc) {
            x[cc] -= mean;
            v2 += x[cc] * x[cc];
        }
        #pragma unroll
        for (int off = 8; off >= 1; off >>= 1) v2 += __shfl_xor(v2, off, 16);
        const float rs = rsqrtf(v2 * (1.f / 64.f) + EPS_LN);
        #pragma unroll
        for (int cc = 0; cc < 4; ++cc) {
            const int c = g + cc * 16;
            yln[patch][c] = x[cc] * rs * gamma[c] + beta[c];
        }
    }
    __syncthreads();

    // ---- KV projection: 256 threads = 2 halves x 128 cols, 8 patches each ----
    {
        const int col = t & 127;
        const int pg = t >> 7;
        #pragma unroll
        for (int pp = 0; pp < 8; ++pp) {
            const int patch = pg * 8 + pp;
            float acc2 = bkv[col];
            #pragma unroll
            for (int c = 0; c < 64; ++c)
                acc2 += yln[patch][c] * Wkv[c * 128 + col];
            const int pglob = ph * 16 + patch;
            if (col < 64)
                Kb[((size_t)b * 256 + pglob) * 64 + col] = f2bf(acc2);
            else
                Vt[((size_t)b * 64 + (col - 64)) * 256 + pglob] = f2bf(acc2);
        }
    }
}

// ---------------- Kernel B: fused MFMA attention ----------------
// grid: BATCH*NQ/64 blocks, 256 threads (4 waves). Wave w: query rows [blk*64+16w, +16).
__global__ __launch_bounds__(256, 3) void attn_mfma(
    const float* __restrict__ inp,          // [B*NQ, 64]
    const unsigned short* __restrict__ Wq_t,// [64][64] bf16, [d][c]
    const float* __restrict__ bq,           // [64]
    const unsigned short* __restrict__ Kb,  // [B,256,64] bf16
    const unsigned short* __restrict__ Vt,  // [B,64,256] bf16
    const unsigned short* __restrict__ Wo_t,// [64][64] bf16, [e][c]
    const float* __restrict__ bo,           // [64]
    float* __restrict__ out)                // [B*NQ, 64]
{
    __shared__ unsigned short Xbuf[4][16][72];
    __shared__ unsigned short Ps[4][16][264];

    const int w    = threadIdx.x >> 6;
    const int lane = threadIdx.x & 63;
    const int l15  = lane & 15;
    const int q4   = lane >> 4;
    const int b    = blockIdx.x >> 8;
    const int m0   = blockIdx.x * 64 + w * 16;

    const float* xrow = inp + (size_t)m0 * 64;
    #pragma unroll
    for (int r = 0; r < 16; ++r)
        Xbuf[w][r][lane] = f2bf(xrow[r * 64 + lane]);

    short8 a0 = *(const short8*)&Xbuf[w][l15][q4 * 8];
    short8 a1 = *(const short8*)&Xbuf[w][l15][32 + q4 * 8];

    f32x4 zero = {0.f, 0.f, 0.f, 0.f};
    f32x4 qacc[4];
    #pragma unroll
    for (int t = 0; t < 4; ++t) {
        const short8 b0 = *(const short8*)(Wq_t + (t * 16 + l15) * 64 + q4 * 8);
        const short8 b1 = *(const short8*)(Wq_t + (t * 16 + l15) * 64 + 32 + q4 * 8);
        qacc[t] = MFMA16(a1, b1, MFMA16(a0, b0, zero));
    }
    #pragma unroll
    for (int t = 0; t < 4; ++t)
        #pragma unroll
        for (int r = 0; r < 4; ++r)
            Xbuf[w][q4 * 4 + r][t * 16 + l15] = f2bf((qacc[t][r] + bq[t * 16 + l15]) * 0.125f);

    short8 qa0 = *(const short8*)&Xbuf[w][l15][q4 * 8];
    short8 qa1 = *(const short8*)&Xbuf[w][l15][32 + q4 * 8];

    const unsigned short* Kbb = Kb + (size_t)b * 256 * 64;
    f32x4 sacc[16];
    #pragma unroll
    for (int t = 0; t < 16; ++t) {
        const short8 b0 = *(const short8*)(Kbb + (t * 16 + l15) * 64 + q4 * 8);
        const short8 b1 = *(const short8*)(Kbb + (t * 16 + l15) * 64 + 32 + q4 * 8);
        sacc[t] = MFMA16(qa1, b1, MFMA16(qa0, b0, zero));
    }

    float mx[4] = {-1e30f, -1e30f, -1e30f, -1e30f};
    #pragma unroll
    for (int t = 0; t < 16; ++t)
        #pragma unroll
        for (int r = 0; r < 4; ++r)
            mx[r] = fmaxf(mx[r], sacc[t][r]);
    #pragma unroll
    for (int r = 0; r < 4; ++r) {
        mx[r] = fmaxf(mx[r], __shfl_xor(mx[r], 1));
        mx[r] = fmaxf(mx[r], __shfl_xor(mx[r], 2));
        mx[r] = fmaxf(mx[r], __shfl_xor(mx[r], 4));
        mx[r] = fmaxf(mx[r], __shfl_xor(mx[r], 8));
    }
    float sm[4] = {0.f, 0.f, 0.f, 0.f};
    #pragma unroll
    for (int t = 0; t < 16; ++t)
        #pragma unroll
        for (int r = 0; r < 4; ++r) {
            float p = __expf(sacc[t][r] - mx[r]);
            sacc[t][r] = p;
            sm[r] += p;
        }
    float inv[4];
    #pragma unroll
    for (int r = 0; r < 4; ++r) {
        sm[r] += __shfl_xor(sm[r], 1);
        sm[r] += __shfl_xor(sm[r], 2);
        sm[r] += __shfl_xor(sm[r], 4);
        sm[r] += __shfl_xor(sm[r], 8);
        inv[r] = 1.f / sm[r];
    }
    #pragma unroll
    for (int t = 0; t < 16; ++t)
        #pragma unroll
        for (int r = 0; r < 4; ++r)
            Ps[w][q4 * 4 + r][t * 16 + l15] = f2bf(sacc[t][r]);

    short8 pa[8];
    #pragma unroll
    for (int kc = 0; kc < 8; ++kc)
        pa[kc] = *(const short8*)&Ps[w][l15][kc * 32 + q4 * 8];

    const unsigned short* Vtb = Vt + (size_t)b * 64 * 256;
    f32x4 oacc[4];
    #pragma unroll
    for (int t = 0; t < 4; ++t) {
        f32x4 acc = zero;
        #pragma unroll
        for (int kc = 0; kc < 8; ++kc) {
            const short8 bf = *(const short8*)(Vtb + (t * 16 + l15) * 256 + kc * 32 + q4 * 8);
            acc = MFMA16(pa[kc], bf, acc);
        }
        oacc[t] = acc;
    }
    #pragma unroll
    for (int t = 0; t < 4; ++t)
        #pragma unroll
        for (int r = 0; r < 4; ++r)
            Xbuf[w][q4 * 4 + r][t * 16 + l15] = f2bf(oacc[t][r] * inv[r]);

    short8 oa0 = *(const short8*)&Xbuf[w][l15][q4 * 8];
    short8 oa1 = *(const short8*)&Xbuf[w][l15][32 + q4 * 8];

    #pragma unroll
    for (int t = 0; t < 4; ++t) {
        const short8 b0 = *(const short8*)(Wo_t + (t * 16 + l15) * 64 + q4 * 8);
        const short8 b1 = *(const short8*)(Wo_t + (t * 16 + l15) * 64 + 32 + q4 * 8);
        f32x4 fin = MFMA16(oa1, b1, MFMA16(oa0, b0, zero));
        const float bias = bo[t * 16 + l15];
        #pragma unroll
        for (int r = 0; r < 4; ++r)
            out[(size_t)(m0 + q4 * 4 + r) * 64 + t * 16 + l15] = fin[r] + bias;
    }
}

extern "C" void kernel_launch(void* const* d_in, const int* in_sizes, int n_in,
                              void* d_out, int out_size, void* d_ws, size_t ws_size,
                              hipStream_t stream) {
    const float* inp     = (const float*)d_in[0];
    const float* Wq      = (const float*)d_in[1];
    const float* bq      = (const float*)d_in[2];
    const float* Wkv     = (const float*)d_in[3];
    const float* bkv     = (const float*)d_in[4];
    const float* Wo      = (const float*)d_in[5];
    const float* bo      = (const float*)d_in[6];
    const float* conv_w  = (const float*)d_in[7];
    const float* conv_b  = (const float*)d_in[8];
    const float* gamma   = (const float*)d_in[9];
    const float* beta    = (const float*)d_in[10];

    char* ws = (char*)d_ws;
    unsigned short* Kb   = (unsigned short*)(ws);                 // 512 KiB
    unsigned short* Vt   = (unsigned short*)(ws + 524288);        // 512 KiB
    unsigned short* Wq_t = (unsigned short*)(ws + 1048576);       // 8 KiB
    unsigned short* Wo_t = (unsigned short*)(ws + 1056768);       // 8 KiB
    unsigned short* Wc_t = (unsigned short*)(ws + 1064960);       // 512 KiB

    prep_kernel<<<64, 256, 0, stream>>>(Wq, Wo, conv_w, Wq_t, Wo_t, Wc_t);
    kv_mfma<<<BATCH * 16, 256, 0, stream>>>(inp, Wc_t, conv_b, gamma, beta,
                                            Wkv, bkv, Kb, Vt);
    attn_mfma<<<(BATCH * NQ) / 64, 256, 0, stream>>>(inp, Wq_t, bq, Kb, Vt,
                                                     Wo_t, bo, (float*)d_out);
}